// Round 17
// baseline (465.045 us; speedup 1.0000x reference)
//
#include <hip/hip_runtime.h>
#include <math.h>

#define PP 128
#define DD 128
#define RR 16384
#define EE 131072
#define TT 1024
#define FF 513
#define FP 520          /* logical f count */
#define FPW 528         /* written f count (pad to full pitch; never gathered) */
#define FPITCH 1056     /* u16 per plane row = 528 complex, 64B-line aligned */
#define NRB 1024        /* segsum row-blocks (16 rows each) */
#define PSTRIDE 528     /* part row stride in float2 */
#define EPITCH 136      /* u16 per col-row of split LDS V planes */

#define TAU_SCALE 46.64723032069971    /* SR / C_SOUND */
#define KDECAY   -0.0211392282f        /* LOG_GAMMA/C - AIR */
#define LOG_GAMMA -6.907755278982137f
#define TWO_PI    6.283185307179586

typedef __attribute__((ext_vector_type(8))) short bf16x8;
typedef __attribute__((ext_vector_type(4))) float f32x4;
typedef unsigned short u16;

__device__ __forceinline__ u16 f2bf(float x) {         // RNE float->bf16 bits
    unsigned u = __float_as_uint(x);
    unsigned r = (u + 0x7fffu + ((u >> 16) & 1u)) >> 16;
    return (u16)r;
}
__device__ __forceinline__ float bf2f(u16 b) {
    return __uint_as_float(((unsigned)b) << 16);
}
// packed (re,im) -> dword of two bf16; HW v_cvt_pk_bf16_f32 when available
__device__ __forceinline__ unsigned pack_bf16(float x, float y) {
#if __has_builtin(__builtin_amdgcn_cvt_pk_bf16_f32)
    auto v = __builtin_amdgcn_cvt_pk_bf16_f32(x, y);   // lo=src0, hi=src1
    unsigned u; __builtin_memcpy(&u, &v, sizeof(u));
    return u;
#else
    return (unsigned)f2bf(x) | ((unsigned)f2bf(y) << 16);
#endif
}

// phase = exp(-2*pi*i * tau * f / 1024). Integer-exact mod-1024 reduction:
// tau = ti + tf (Sterbenz-exact), (ti*f) mod 1024 in int, residual tf*f
// in fp32 (abs err ~6e-5 -> ~4e-7 rad). No f64.
__device__ __forceinline__ void pf_sincos(float tau, int f, float* s, float* c) {
    int ti = (int)tau;
    float tf = tau - (float)ti;
    int m = (ti * f) & 1023;
    float u = fmaf(tf, (float)f, (float)m);
    float ang = u * -0.006135923151542565f;          // -2*pi/1024
    __sincosf(ang, s, c);
}

// ---- merged setup: [0,8192) build Kh/Kl (pre-split bf16 hi/lo, fragment
// layout), [8192,8256) per-row precompute, [8256,8768) edge count.
__global__ void k_setup(const float* __restrict__ rpos,
                        const float* __restrict__ spos,
                        const float* __restrict__ cpos,
                        const float* __restrict__ avg_dist,
                        float* __restrict__ per_row,
                        const float* __restrict__ absorption,
                        const float* __restrict__ scattering,
                        const int* __restrict__ object_ids,
                        const float* __restrict__ basis,
                        u16* __restrict__ Kh, u16* __restrict__ Kl,
                        const int* __restrict__ gk_row,
                        int* __restrict__ counts) {
    int b = blockIdx.x;
    if (b < 8192) {
        int idx = b * 256 + threadIdx.x;    // p*16384 + d*128 + e
        int p  = idx >> 14;
        int de = idx & 16383;
        int obj = object_ids[p];
        float refl = 1.0f - absorption[obj];
        float sc   = scattering[obj];
        float kv = refl*sc*basis[de] + refl*(1.0f - sc)*basis[16384 + de];
        u16 hb = f2bf(kv);
        Kh[idx] = hb;
        Kl[idx] = f2bf(kv - bf2f(hb));
    } else if (b < 8256) {
        int r = (b - 8192) * 256 + threadIdx.x;
        float x = rpos[3*r], y = rpos[3*r+1], z = rpos[3*r+2];
        float dx = x - spos[0], dy = y - spos[1], dz = z - spos[2];
        float ds = sqrtf(dx*dx + dy*dy + dz*dz);
        per_row[0*RR + r] = (1.0f/(ds*ds + 0.001f)) * expf(KDECAY * ds);
        per_row[1*RR + r] = ds * (float)TAU_SCALE;
        dx = x - cpos[0]; dy = y - cpos[1]; dz = z - cpos[2];
        float dr = sqrtf(dx*dx + dy*dy + dz*dz);
        per_row[2*RR + r] = (1.0f/(dr*dr + 0.001f)) * expf(KDECAY * dr);
        per_row[3*RR + r] = dr * (float)TAU_SCALE;
        float da = avg_dist[r];
        per_row[4*RR + r] = expf(KDECAY * da);
        per_row[5*RR + r] = da * (float)TAU_SCALE;
    } else {
        int e = (b - 8256) * 256 + threadIdx.x;
        atomicAdd(&counts[gk_row[e]], 1);
    }
}

__global__ __launch_bounds__(1024) void k_scan(const int* __restrict__ counts,
                                               int* __restrict__ row_start,
                                               int* __restrict__ cursor) {
    __shared__ int sh[1024];
    int tid = threadIdx.x;
    int base = tid * 16;
    int local[16];
    int sum = 0;
    #pragma unroll
    for (int j = 0; j < 16; j++) { local[j] = sum; sum += counts[base + j]; }
    sh[tid] = sum;
    __syncthreads();
    for (int off = 1; off < 1024; off <<= 1) {
        int v = (tid >= off) ? sh[tid - off] : 0;
        __syncthreads();
        sh[tid] += v;
        __syncthreads();
    }
    int chunk_excl = sh[tid] - sum;   // exclusive prefix of this 16-chunk
    #pragma unroll
    for (int j = 0; j < 16; j++) {
        int v = chunk_excl + local[j];
        row_start[base + j] = v;
        cursor[base + j] = v;
    }
    if (tid == 1023) row_start[RR] = chunk_excl + sum;
}

// scatter packing {col, val} per edge -> one b64 load in segsum
__global__ void k_scatter(const int* __restrict__ gk_row,
                          const float* __restrict__ gk_val,
                          const int* __restrict__ gk_col,
                          int* __restrict__ cursor,
                          int2* __restrict__ edge) {
    int e = blockIdx.x * 256 + threadIdx.x;
    int pos = atomicAdd(&cursor[gk_row[e]], 1);
    edge[pos] = make_int2(gk_col[e], __float_as_int(gk_val[e]));
}

// ---- init with delta-f=64 rotators: 4 sincos/row (vs 2/element).
__global__ __launch_bounds__(256) void k_init(const float* __restrict__ per_row,
                                              u16* __restrict__ cur,
                                              float* __restrict__ echo) {
    __shared__ float2 sh[4][64][9];
    int fl = threadIdx.x & 63, rg = threadIdx.x >> 6;
    int r0 = blockIdx.x * 32;
    float2 eacc[9];
    #pragma unroll
    for (int k = 0; k < 9; k++) eacc[k] = make_float2(0.f, 0.f);

    for (int i = 0; i < 8; i++) {
        int r = r0 + rg + i * 4;
        float amp = per_row[r],      tau  = per_row[RR + r];
        float w   = per_row[2*RR+r], taur = per_row[3*RR + r];
        float s1, c1, rs1, rc1, s2, c2, rs2, rc2;
        pf_sincos(tau,  fl, &s1, &c1);  pf_sincos(tau,  64, &rs1, &rc1);
        pf_sincos(taur, fl, &s2, &c2);  pf_sincos(taur, 64, &rs2, &rc2);
        u16* wrow = cur + (size_t)r * FPITCH;
        #pragma unroll
        for (int k = 0; k < 9; k++) {
            int f = fl + (k << 6);
            float re = amp * c1, im = amp * s1;
            if (f < FPW)
                *(unsigned*)(wrow + f * 2) = pack_bf16(re, im);
            if (f < FF) {
                eacc[k].x = fmaf(w, c2*re - s2*im, eacc[k].x);
                eacc[k].y = fmaf(w, c2*im + s2*re, eacc[k].y);
            }
            float n1c = c1*rc1 - s1*rs1, n1s = s1*rc1 + c1*rs1;
            c1 = n1c; s1 = n1s;
            float n2c = c2*rc2 - s2*rs2, n2s = s2*rc2 + c2*rs2;
            c2 = n2c; s2 = n2s;
        }
    }
    #pragma unroll
    for (int k = 0; k < 9; k++) sh[rg][fl][k] = eacc[k];
    __syncthreads();
    if (rg == 0) {
        #pragma unroll
        for (int k = 0; k < 9; k++) {
            int f = fl + (k << 6);
            if (f < FF) {
                float sx = sh[0][fl][k].x + sh[1][fl][k].x + sh[2][fl][k].x + sh[3][fl][k].x;
                float sy = sh[0][fl][k].y + sh[1][fl][k].y + sh[2][fl][k].y + sh[3][fl][k].y;
                atomicAdd(&echo[2*f],   sx);
                atomicAdd(&echo[2*f+1], sy);
            }
        }
    }
}

// ---- matmul + prop via MFMA, bf16 planes, SPLIT re/im LDS.
// A-fragments loaded DIRECTLY from pre-split Kh/Kl (one b128 each). Grid 1024
// = 128 p x 8 chunks (XCD-swizzled on p); chunk q covers complex-tiles ct (16
// complex f): q<7 -> 4, q=7 -> 5 (pad cols 520..527 written, never gathered).
// Lane n holds re+im of f=ct*16+n: no-shfl epilogue, HW-packed dword stores.
__global__ __launch_bounds__(256) void k_matmul(const u16* __restrict__ Kh,
                                                const u16* __restrict__ Kl,
                                                const u16* __restrict__ in,
                                                const float* __restrict__ per_row,
                                                u16* __restrict__ out) {
    __shared__ u16 relds[2][16 * EPITCH];
    __shared__ u16 imlds[2][16 * EPITCH];
    int b = blockIdx.x;
    int xcd = b & 7;
    int g = b >> 3;                  // 0..127
    int p = (g >> 3) * 8 + xcd;
    int q = g & 7;
    int ct0 = q * 4;
    int ctEnd = (q == 7) ? 33 : ct0 + 4;

    int tid  = threadIdx.x;
    int wave = tid >> 6;
    int lane = tid & 63;
    int quad = lane >> 4;
    int n    = lane & 15;
    int mt0  = wave << 1;

    // A fragments: direct b128 loads from pre-split matrices
    bf16x8 Ah[2][4], Al[2][4];
    #pragma unroll
    for (int mi = 0; mi < 2; mi++) {
        size_t rowoff = (size_t)(p << 14) + ((mt0 + mi) * 16 + n) * 128 + quad * 8;
        #pragma unroll
        for (int kt = 0; kt < 4; kt++) {
            Ah[mi][kt] = *(const bf16x8*)(Kh + rowoff + kt * 32);
            Al[mi][kt] = *(const bf16x8*)(Kl + rowoff + kt * 32);
        }
    }
    // per-output-row prop constants + phase rotators (f advances 16 per ct)
    float dec_[2][4];
    float pc[2][4], ps[2][4];        // current phase (cos, sin)
    float rc[2][4], rs[2][4];        // step rotator (delta-f = 16)
    #pragma unroll
    for (int mi = 0; mi < 2; mi++)
        #pragma unroll
        for (int r = 0; r < 4; r++) {
            int row = (p << 7) + (mt0 + mi) * 16 + quad * 4 + r;
            dec_[mi][r] = per_row[4*RR + row];
            float tau = per_row[5*RR + row];
            pf_sincos(tau, ct0 * 16 + n, &ps[mi][r], &pc[mi][r]);
            pf_sincos(tau, 16, &rs[mi][r], &rc[mi][r]);
        }

    const u16* pin = in + (size_t)(p << 7) * FPITCH;
    uint4 pk0, pk1;
    int se = tid >> 1, h = tid & 1;      // staging: e-row, 8-complex half
    auto loadTile = [&](int ct) {
        const u16* src = pin + (size_t)se * FPITCH + ct * 32 + h * 16;
        pk0 = *(const uint4*)(src);
        pk1 = *(const uint4*)(src + 8);
    };
    auto writeTile = [&](int buf) {
        unsigned w[8] = {pk0.x, pk0.y, pk0.z, pk0.w, pk1.x, pk1.y, pk1.z, pk1.w};
        int cbase = h * 8;
        #pragma unroll
        for (int k = 0; k < 8; k++) {
            int col = cbase + k;             // w[k] = (re, im) of complex col
            relds[buf][col * EPITCH + se] = (u16)(w[k] & 0xffffu);
            imlds[buf][col * EPITCH + se] = (u16)(w[k] >> 16);
        }
    };

    loadTile(ct0); writeTile(0);
    for (int ct = ct0; ct < ctEnd; ct++) {
        int cb = (ct - ct0) & 1;
        __syncthreads();                    // planes[cb] ready for read
        if (ct + 1 < ctEnd) { loadTile(ct + 1); writeTile(cb ^ 1); }

        f32x4 ar0 = {0.f,0.f,0.f,0.f}, ar1 = {0.f,0.f,0.f,0.f};
        f32x4 ai0 = {0.f,0.f,0.f,0.f}, ai1 = {0.f,0.f,0.f,0.f};
        const u16* vr = &relds[cb][n * EPITCH];
        const u16* vi = &imlds[cb][n * EPITCH];
        #pragma unroll
        for (int kt = 0; kt < 4; kt++) {
            bf16x8 Br = *(const bf16x8*)(vr + kt * 32 + quad * 8);
            bf16x8 Bi = *(const bf16x8*)(vi + kt * 32 + quad * 8);
            ar0 = __builtin_amdgcn_mfma_f32_16x16x32_bf16(Ah[0][kt], Br, ar0, 0,0,0);
            ar1 = __builtin_amdgcn_mfma_f32_16x16x32_bf16(Ah[1][kt], Br, ar1, 0,0,0);
            ai0 = __builtin_amdgcn_mfma_f32_16x16x32_bf16(Ah[0][kt], Bi, ai0, 0,0,0);
            ai1 = __builtin_amdgcn_mfma_f32_16x16x32_bf16(Ah[1][kt], Bi, ai1, 0,0,0);
            ar0 = __builtin_amdgcn_mfma_f32_16x16x32_bf16(Al[0][kt], Br, ar0, 0,0,0);
            ar1 = __builtin_amdgcn_mfma_f32_16x16x32_bf16(Al[1][kt], Br, ar1, 0,0,0);
            ai0 = __builtin_amdgcn_mfma_f32_16x16x32_bf16(Al[0][kt], Bi, ai0, 0,0,0);
            ai1 = __builtin_amdgcn_mfma_f32_16x16x32_bf16(Al[1][kt], Bi, ai1, 0,0,0);
        }

        // prop epilogue: both re and im in-lane -> no shfl; HW-packed store
        int f = ct * 16 + n;                // complex f, < 528
        #pragma unroll
        for (int mi = 0; mi < 2; mi++) {
            f32x4 are = mi ? ar1 : ar0;
            f32x4 aim = mi ? ai1 : ai0;
            #pragma unroll
            for (int r = 0; r < 4; r++) {
                float re = are[r], im = aim[r];
                float s = ps[mi][r], c = pc[mi][r];
                float ore = dec_[mi][r] * (c*re - s*im);
                float oim = dec_[mi][r] * (c*im + s*re);
                int row = (p << 7) + (mt0 + mi) * 16 + quad * 4 + r;
                *(unsigned*)(out + (size_t)row * FPITCH + f * 2) =
                    pack_bf16(ore, oim);
                // advance rotator by delta-f = 16
                float nc = c*rc[mi][r] - s*rs[mi][r];
                float nsv = s*rc[mi][r] + c*rs[mi][r];
                pc[mi][r] = nc; ps[mi][r] = nsv;
            }
        }
    }
}

// ---- segment sum + fused receiver-echo epilogue (bf16 planes, R12-proven).
// 1024 blocks x 512 thr = 128 fl x 4 ry; each ry processes 4 rows
// sequentially. 4 slices/lane + 2x edge unroll = 8 loads in flight. Echo
// partials in registers; one part write per block.
__global__ __launch_bounds__(512) void k_segsum(const int* __restrict__ row_start,
                                                const int2* __restrict__ edge,
                                                const u16* __restrict__ in,
                                                u16* __restrict__ outp,
                                                const float* __restrict__ per_row,
                                                float2* __restrict__ part,
                                                int store_cur) {
    __shared__ float2 sh[4][128][5];
    int rb = blockIdx.x;
    int fl = threadIdx.x & 127, ry = threadIdx.x >> 7;
    bool tail = (fl < 8);
    float2 e0 = {0.f,0.f}, e1 = {0.f,0.f}, e2 = {0.f,0.f}, e3 = {0.f,0.f}, e4 = {0.f,0.f};

    for (int i = 0; i < 4; i++) {
        int row = (rb << 4) + (ry << 2) + i;
        int s0 = row_start[row], s1 = row_start[row + 1];
        float a0r=0.f,a0i=0.f,a1r=0.f,a1i=0.f,a2r=0.f,a2i=0.f,a3r=0.f,a3i=0.f;
        float t4r=0.f,t4i=0.f;
        int t = s0;
        for (; t + 1 < s1; t += 2) {
            int2 ed0 = edge[t], ed1 = edge[t+1];
            float v0 = __int_as_float(ed0.y), v1 = __int_as_float(ed1.y);
            const u16* g0p = in + (size_t)ed0.x * FPITCH + (fl << 1);
            const u16* g1p = in + (size_t)ed1.x * FPITCH + (fl << 1);
            unsigned b00 = *(const unsigned*)(g0p);
            unsigned b01 = *(const unsigned*)(g0p + 256);
            unsigned b02 = *(const unsigned*)(g0p + 512);
            unsigned b03 = *(const unsigned*)(g0p + 768);
            unsigned b10 = *(const unsigned*)(g1p);
            unsigned b11 = *(const unsigned*)(g1p + 256);
            unsigned b12 = *(const unsigned*)(g1p + 512);
            unsigned b13 = *(const unsigned*)(g1p + 768);
            a0r = fmaf(v0, bf2f((u16)(b00 & 0xffffu)), a0r); a0i = fmaf(v0, bf2f((u16)(b00 >> 16)), a0i);
            a1r = fmaf(v0, bf2f((u16)(b01 & 0xffffu)), a1r); a1i = fmaf(v0, bf2f((u16)(b01 >> 16)), a1i);
            a2r = fmaf(v0, bf2f((u16)(b02 & 0xffffu)), a2r); a2i = fmaf(v0, bf2f((u16)(b02 >> 16)), a2i);
            a3r = fmaf(v0, bf2f((u16)(b03 & 0xffffu)), a3r); a3i = fmaf(v0, bf2f((u16)(b03 >> 16)), a3i);
            a0r = fmaf(v1, bf2f((u16)(b10 & 0xffffu)), a0r); a0i = fmaf(v1, bf2f((u16)(b10 >> 16)), a0i);
            a1r = fmaf(v1, bf2f((u16)(b11 & 0xffffu)), a1r); a1i = fmaf(v1, bf2f((u16)(b11 >> 16)), a1i);
            a2r = fmaf(v1, bf2f((u16)(b12 & 0xffffu)), a2r); a2i = fmaf(v1, bf2f((u16)(b12 >> 16)), a2i);
            a3r = fmaf(v1, bf2f((u16)(b13 & 0xffffu)), a3r); a3i = fmaf(v1, bf2f((u16)(b13 >> 16)), a3i);
            if (tail) {
                unsigned b04 = *(const unsigned*)(g0p + 1024);
                unsigned b14 = *(const unsigned*)(g1p + 1024);
                t4r = fmaf(v0, bf2f((u16)(b04 & 0xffffu)), t4r); t4i = fmaf(v0, bf2f((u16)(b04 >> 16)), t4i);
                t4r = fmaf(v1, bf2f((u16)(b14 & 0xffffu)), t4r); t4i = fmaf(v1, bf2f((u16)(b14 >> 16)), t4i);
            }
        }
        if (t < s1) {
            int2 ed = edge[t];
            float v = __int_as_float(ed.y);
            const u16* g = in + (size_t)ed.x * FPITCH + (fl << 1);
            unsigned b0 = *(const unsigned*)(g);
            unsigned b1 = *(const unsigned*)(g + 256);
            unsigned b2 = *(const unsigned*)(g + 512);
            unsigned b3 = *(const unsigned*)(g + 768);
            a0r = fmaf(v, bf2f((u16)(b0 & 0xffffu)), a0r); a0i = fmaf(v, bf2f((u16)(b0 >> 16)), a0i);
            a1r = fmaf(v, bf2f((u16)(b1 & 0xffffu)), a1r); a1i = fmaf(v, bf2f((u16)(b1 >> 16)), a1i);
            a2r = fmaf(v, bf2f((u16)(b2 & 0xffffu)), a2r); a2i = fmaf(v, bf2f((u16)(b2 >> 16)), a2i);
            a3r = fmaf(v, bf2f((u16)(b3 & 0xffffu)), a3r); a3i = fmaf(v, bf2f((u16)(b3 >> 16)), a3i);
            if (tail) {
                unsigned b4 = *(const unsigned*)(g + 1024);
                t4r = fmaf(v, bf2f((u16)(b4 & 0xffffu)), t4r); t4i = fmaf(v, bf2f((u16)(b4 >> 16)), t4i);
            }
        }
        if (store_cur) {
            u16* w = outp + (size_t)row * FPITCH + (fl << 1);
            *(unsigned*)(w)       = pack_bf16(a0r, a0i);
            *(unsigned*)(w + 256) = pack_bf16(a1r, a1i);
            *(unsigned*)(w + 512) = pack_bf16(a2r, a2i);
            *(unsigned*)(w + 768) = pack_bf16(a3r, a3i);
            if (tail)
                *(unsigned*)(w + 1024) = pack_bf16(t4r, t4i);
        }
        // echo: contrib(f) = w_rec * phase(tau_rec, f) * value, into registers
        float wr = per_row[2*RR + row], taur = per_row[3*RR + row];
        float s, c;
        pf_sincos(taur, fl, &s, &c);
        e0.x = fmaf(wr, c*a0r - s*a0i, e0.x); e0.y = fmaf(wr, c*a0i + s*a0r, e0.y);
        pf_sincos(taur, fl + 128, &s, &c);
        e1.x = fmaf(wr, c*a1r - s*a1i, e1.x); e1.y = fmaf(wr, c*a1i + s*a1r, e1.y);
        pf_sincos(taur, fl + 256, &s, &c);
        e2.x = fmaf(wr, c*a2r - s*a2i, e2.x); e2.y = fmaf(wr, c*a2i + s*a2r, e2.y);
        pf_sincos(taur, fl + 384, &s, &c);
        e3.x = fmaf(wr, c*a3r - s*a3i, e3.x); e3.y = fmaf(wr, c*a3i + s*a3r, e3.y);
        if (tail && (512 + fl) < FF) {       // f=512 only
            pf_sincos(taur, 512 + fl, &s, &c);
            e4.x = fmaf(wr, c*t4r - s*t4i, e4.x); e4.y = fmaf(wr, c*t4i + s*t4r, e4.y);
        }
    }
    sh[ry][fl][0] = e0; sh[ry][fl][1] = e1; sh[ry][fl][2] = e2;
    sh[ry][fl][3] = e3; sh[ry][fl][4] = e4;
    __syncthreads();
    if (ry == 0) {
        float2* pp = part + (size_t)rb * PSTRIDE;
        #pragma unroll
        for (int sidx = 0; sidx < 5; sidx++) {
            int fidx = sidx * 128 + fl;
            if (fidx < FP) {
                float2 v0 = sh[0][fl][sidx], v1 = sh[1][fl][sidx];
                float2 v2 = sh[2][fl][sidx], v3 = sh[3][fl][sidx];
                float2 acc = pp[fidx];
                acc.x += v0.x + v1.x + v2.x + v3.x;
                acc.y += v0.y + v1.y + v2.y + v3.y;
                pp[fidx] = acc;
            }
        }
    }
}

// ---- fold echo partials: echo[f] += sum_rb part[rb][f]
__global__ __launch_bounds__(256) void k_fold(const float2* __restrict__ part,
                                              float* __restrict__ echo) {
    int f = blockIdx.x;     // 0..FF-1
    float sx = 0.f, sy = 0.f;
    for (int rb = threadIdx.x; rb < NRB; rb += 256) {
        float2 v = part[(size_t)rb * PSTRIDE + f];
        sx += v.x; sy += v.y;
    }
    for (int off = 32; off >= 1; off >>= 1) {
        sx += __shfl_down(sx, off, 64);
        sy += __shfl_down(sy, off, 64);
    }
    __shared__ float red[2][4];
    int lane = threadIdx.x & 63, w = threadIdx.x >> 6;
    if (lane == 0) { red[0][w] = sx; red[1][w] = sy; }
    __syncthreads();
    if (threadIdx.x == 0) {
        sx = red[0][0]+red[0][1]+red[0][2]+red[0][3];
        sy = red[1][0]+red[1][1]+red[1][2]+red[1][3];
        echo[2*f] += sx;
        echo[2*f+1] += sy;
    }
}

// ---- irfft(n=1024) / fsm_window
__global__ void k_irfft(const float* __restrict__ echo, float* __restrict__ out) {
    int t = blockIdx.x * blockDim.x + threadIdx.x;   // 0..1023
    float acc = echo[0];                              // f=0 (real)
    float nyq = echo[2 * 512];                        // Nyquist real part
    acc += (t & 1) ? -nyq : nyq;
    for (int f = 1; f < 512; f++) {
        int m = (f * t) & 1023;
        float ang = (float)m * 0.006135923151542565f;  // 2*pi/1024
        float s, c; __sincosf(ang, &s, &c);
        acc += 2.0f * (echo[2*f]*c - echo[2*f+1]*s);
    }
    acc *= (1.0f / 1024.0f);
    float tsec = (float)t * (1.0f / 16000.0f);
    float win = expf(LOG_GAMMA * tsec);
    out[t] = acc / win;
}

extern "C" void kernel_launch(void* const* d_in, const int* in_sizes, int n_in,
                              void* d_out, int out_size, void* d_ws, size_t ws_size,
                              hipStream_t stream) {
    const float* source_pos   = (const float*)d_in[0];
    const float* receiver_pos = (const float*)d_in[1];
    const float* absorption   = (const float*)d_in[2];
    const float* scattering   = (const float*)d_in[3];
    const float* gk_val       = (const float*)d_in[4];
    const float* basis        = (const float*)d_in[5];
    const float* avg_dist     = (const float*)d_in[6];
    const float* rpos         = (const float*)d_in[7];
    const int*   gk_row       = (const int*)d_in[8];
    const int*   gk_col       = (const int*)d_in[9];
    const int*   object_ids   = (const int*)d_in[10];
    float* out = (float*)d_out;

    char* base = (char*)d_ws;
    size_t off = 0;
    auto alloc = [&](size_t bytes) -> void* {
        void* ptr = base + off;
        off = (off + bytes + 255) & ~(size_t)255;
        return ptr;
    };
    const size_t PLANE = (size_t)RR * FPITCH + FPITCH;   // +1 row slack
    u16*    Kh        = (u16*)alloc(sizeof(u16) * PP * DD * DD);
    u16*    Kl        = (u16*)alloc(sizeof(u16) * PP * DD * DD);
    u16*    cur       = (u16*)alloc(sizeof(u16) * PLANE);
    u16*    nxt       = (u16*)alloc(sizeof(u16) * PLANE);
    float*  per_row   = (float*)alloc(sizeof(float) * 6 * RR);
    int*    row_start = (int*)alloc(sizeof(int) * (RR + 1));
    int*    cursor    = (int*)alloc(sizeof(int) * RR);
    int2*   edge      = (int2*)alloc(sizeof(int2) * EE);
    // part, echo, counts contiguous -> one memset covers all three
    float2* part      = (float2*)alloc(sizeof(float2) * NRB * PSTRIDE);
    float*  echo      = (float*)alloc(sizeof(float) * 1056);
    int*    counts    = (int*)alloc(sizeof(int) * RR);
    size_t  zspan     = (size_t)((char*)(counts + RR) - (char*)part);

    hipMemsetAsync(part, 0, zspan, stream);

    k_setup<<<8768, 256, 0, stream>>>(rpos, source_pos, receiver_pos, avg_dist,
                                      per_row, absorption, scattering,
                                      object_ids, basis, Kh, Kl, gk_row, counts);
    k_scan<<<1, 1024, 0, stream>>>(counts, row_start, cursor);
    k_scatter<<<EE / 256, 256, 0, stream>>>(gk_row, gk_val, gk_col, cursor, edge);
    k_init<<<512, 256, 0, stream>>>(per_row, cur, echo);

    for (int b = 0; b < 4; b++) {
        k_matmul<<<1024, 256, 0, stream>>>(Kh, Kl, cur, per_row, nxt);
        k_segsum<<<NRB, 512, 0, stream>>>(row_start, edge, nxt, cur,
                                          per_row, part, (b < 3) ? 1 : 0);
    }

    k_fold<<<FF, 256, 0, stream>>>(part, echo);
    k_irfft<<<4, 256, 0, stream>>>(echo, out);
}

// Round 18
// 456.275 us; speedup vs baseline: 1.0192x; 1.0192x over previous
//
#include <hip/hip_runtime.h>
#include <math.h>

#define PP 128
#define DD 128
#define RR 16384
#define EE 131072
#define TT 1024
#define FF 513
#define FP 520          /* logical f count */
#define FPW 528         /* written f count (pad to full pitch; never gathered) */
#define FPITCH 1056     /* u16 per plane row = 528 complex, 64B-line aligned */
#define NRB 512         /* segsum row-blocks (32 rows each) */
#define PSTRIDE 528     /* part row stride in float2 */
#define EPITCH 136      /* u16 per col-row of split LDS V planes */

#define TAU_SCALE 46.64723032069971    /* SR / C_SOUND */
#define KDECAY   -0.0211392282f        /* LOG_GAMMA/C - AIR */
#define LOG_GAMMA -6.907755278982137f
#define TWO_PI    6.283185307179586

typedef __attribute__((ext_vector_type(8))) short bf16x8;
typedef __attribute__((ext_vector_type(4))) float f32x4;
typedef unsigned short u16;

__device__ __forceinline__ u16 f2bf(float x) {         // RNE float->bf16 bits
    unsigned u = __float_as_uint(x);
    unsigned r = (u + 0x7fffu + ((u >> 16) & 1u)) >> 16;
    return (u16)r;
}
__device__ __forceinline__ float bf2f(u16 b) {
    return __uint_as_float(((unsigned)b) << 16);
}
// packed (re,im) -> dword of two bf16; HW v_cvt_pk_bf16_f32 when available
__device__ __forceinline__ unsigned pack_bf16(float x, float y) {
#if __has_builtin(__builtin_amdgcn_cvt_pk_bf16_f32)
    auto v = __builtin_amdgcn_cvt_pk_bf16_f32(x, y);   // lo=src0, hi=src1
    unsigned u; __builtin_memcpy(&u, &v, sizeof(u));
    return u;
#else
    return (unsigned)f2bf(x) | ((unsigned)f2bf(y) << 16);
#endif
}

// phase = exp(-2*pi*i * tau * f / 1024). Integer-exact mod-1024 reduction:
// tau = ti + tf (Sterbenz-exact), (ti*f) mod 1024 in int, residual tf*f
// in fp32 (abs err ~6e-5 -> ~4e-7 rad). No f64.
__device__ __forceinline__ void pf_sincos(float tau, int f, float* s, float* c) {
    int ti = (int)tau;
    float tf = tau - (float)ti;
    int m = (ti * f) & 1023;
    float u = fmaf(tf, (float)f, (float)m);
    float ang = u * -0.006135923151542565f;          // -2*pi/1024
    __sincosf(ang, s, c);
}

// ---- merged setup: [0,8192) build Kh/Kl (pre-split bf16 hi/lo, fragment
// layout), [8192,8256) per-row precompute, [8256,8768) edge count.
__global__ void k_setup(const float* __restrict__ rpos,
                        const float* __restrict__ spos,
                        const float* __restrict__ cpos,
                        const float* __restrict__ avg_dist,
                        float* __restrict__ per_row,
                        const float* __restrict__ absorption,
                        const float* __restrict__ scattering,
                        const int* __restrict__ object_ids,
                        const float* __restrict__ basis,
                        u16* __restrict__ Kh, u16* __restrict__ Kl,
                        const int* __restrict__ gk_row,
                        int* __restrict__ counts) {
    int b = blockIdx.x;
    if (b < 8192) {
        int idx = b * 256 + threadIdx.x;    // p*16384 + d*128 + e
        int p  = idx >> 14;
        int de = idx & 16383;
        int obj = object_ids[p];
        float refl = 1.0f - absorption[obj];
        float sc   = scattering[obj];
        float kv = refl*sc*basis[de] + refl*(1.0f - sc)*basis[16384 + de];
        u16 hb = f2bf(kv);
        Kh[idx] = hb;
        Kl[idx] = f2bf(kv - bf2f(hb));
    } else if (b < 8256) {
        int r = (b - 8192) * 256 + threadIdx.x;
        float x = rpos[3*r], y = rpos[3*r+1], z = rpos[3*r+2];
        float dx = x - spos[0], dy = y - spos[1], dz = z - spos[2];
        float ds = sqrtf(dx*dx + dy*dy + dz*dz);
        per_row[0*RR + r] = (1.0f/(ds*ds + 0.001f)) * expf(KDECAY * ds);
        per_row[1*RR + r] = ds * (float)TAU_SCALE;
        dx = x - cpos[0]; dy = y - cpos[1]; dz = z - cpos[2];
        float dr = sqrtf(dx*dx + dy*dy + dz*dz);
        per_row[2*RR + r] = (1.0f/(dr*dr + 0.001f)) * expf(KDECAY * dr);
        per_row[3*RR + r] = dr * (float)TAU_SCALE;
        float da = avg_dist[r];
        per_row[4*RR + r] = expf(KDECAY * da);
        per_row[5*RR + r] = da * (float)TAU_SCALE;
    } else {
        int e = (b - 8256) * 256 + threadIdx.x;
        atomicAdd(&counts[gk_row[e]], 1);
    }
}

__global__ __launch_bounds__(1024) void k_scan(const int* __restrict__ counts,
                                               int* __restrict__ row_start,
                                               int* __restrict__ cursor) {
    __shared__ int sh[1024];
    int tid = threadIdx.x;
    int base = tid * 16;
    int local[16];
    int sum = 0;
    #pragma unroll
    for (int j = 0; j < 16; j++) { local[j] = sum; sum += counts[base + j]; }
    sh[tid] = sum;
    __syncthreads();
    for (int off = 1; off < 1024; off <<= 1) {
        int v = (tid >= off) ? sh[tid - off] : 0;
        __syncthreads();
        sh[tid] += v;
        __syncthreads();
    }
    int chunk_excl = sh[tid] - sum;   // exclusive prefix of this 16-chunk
    #pragma unroll
    for (int j = 0; j < 16; j++) {
        int v = chunk_excl + local[j];
        row_start[base + j] = v;
        cursor[base + j] = v;
    }
    if (tid == 1023) row_start[RR] = chunk_excl + sum;
}

// ---- merged scatter + init: blocks [0,512) scatter edges; [512,1024) init.
__global__ __launch_bounds__(256) void k_scatter_init(
                          const int* __restrict__ gk_row,
                          const float* __restrict__ gk_val,
                          const int* __restrict__ gk_col,
                          int* __restrict__ cursor,
                          int2* __restrict__ edge,
                          const float* __restrict__ per_row,
                          u16* __restrict__ cur,
                          float* __restrict__ echo) {
    int b = blockIdx.x;
    if (b < 512) {
        int e = b * 256 + threadIdx.x;
        int pos = atomicAdd(&cursor[gk_row[e]], 1);
        edge[pos] = make_int2(gk_col[e], __float_as_int(gk_val[e]));
        return;
    }
    // ---- init with delta-f=64 rotators: 4 sincos/row (vs 2/element).
    __shared__ float2 sh[4][64][9];
    int fl = threadIdx.x & 63, rg = threadIdx.x >> 6;
    int r0 = (b - 512) * 32;
    float2 eacc[9];
    #pragma unroll
    for (int k = 0; k < 9; k++) eacc[k] = make_float2(0.f, 0.f);

    for (int i = 0; i < 8; i++) {
        int r = r0 + rg + i * 4;
        float amp = per_row[r],      tau  = per_row[RR + r];
        float w   = per_row[2*RR+r], taur = per_row[3*RR + r];
        float s1, c1, rs1, rc1, s2, c2, rs2, rc2;
        pf_sincos(tau,  fl, &s1, &c1);  pf_sincos(tau,  64, &rs1, &rc1);
        pf_sincos(taur, fl, &s2, &c2);  pf_sincos(taur, 64, &rs2, &rc2);
        u16* wrow = cur + (size_t)r * FPITCH;
        #pragma unroll
        for (int k = 0; k < 9; k++) {
            int f = fl + (k << 6);
            float re = amp * c1, im = amp * s1;
            if (f < FPW)
                *(unsigned*)(wrow + f * 2) = pack_bf16(re, im);
            if (f < FF) {
                eacc[k].x = fmaf(w, c2*re - s2*im, eacc[k].x);
                eacc[k].y = fmaf(w, c2*im + s2*re, eacc[k].y);
            }
            float n1c = c1*rc1 - s1*rs1, n1s = s1*rc1 + c1*rs1;
            c1 = n1c; s1 = n1s;
            float n2c = c2*rc2 - s2*rs2, n2s = s2*rc2 + c2*rs2;
            c2 = n2c; s2 = n2s;
        }
    }
    #pragma unroll
    for (int k = 0; k < 9; k++) sh[rg][fl][k] = eacc[k];
    __syncthreads();
    if (rg == 0) {
        #pragma unroll
        for (int k = 0; k < 9; k++) {
            int f = fl + (k << 6);
            if (f < FF) {
                float sx = sh[0][fl][k].x + sh[1][fl][k].x + sh[2][fl][k].x + sh[3][fl][k].x;
                float sy = sh[0][fl][k].y + sh[1][fl][k].y + sh[2][fl][k].y + sh[3][fl][k].y;
                atomicAdd(&echo[2*f],   sx);
                atomicAdd(&echo[2*f+1], sy);
            }
        }
    }
}

// ---- matmul + prop via MFMA, bf16 planes, SPLIT re/im LDS.
// A-fragments loaded DIRECTLY from pre-split Kh/Kl (one b128 each). Grid 512
// = 128 p x 4 chunks (XCD-swizzled on p); chunk q covers 8 complex-tiles ct
// (16 complex f each), q=3 covers 9 (pad cols 520..527 written, never
// gathered). Halved chunk count amortizes the ~2K-cyc prologue (K loads +
// 24 sincos) over 2x tiles and halves redundant K fetch.
// Lane n holds re+im of f=ct*16+n: no-shfl epilogue, packed dword stores.
__global__ __launch_bounds__(256) void k_matmul(const u16* __restrict__ Kh,
                                                const u16* __restrict__ Kl,
                                                const u16* __restrict__ in,
                                                const float* __restrict__ per_row,
                                                u16* __restrict__ out) {
    __shared__ u16 relds[2][16 * EPITCH];
    __shared__ u16 imlds[2][16 * EPITCH];
    int b = blockIdx.x;
    int xcd = b & 7;
    int g = b >> 3;                  // 0..63
    int p = (g >> 2) * 8 + xcd;
    int q = g & 3;
    int ct0 = q * 8;
    int ctEnd = (q == 3) ? 33 : ct0 + 8;

    int tid  = threadIdx.x;
    int wave = tid >> 6;
    int lane = tid & 63;
    int quad = lane >> 4;
    int n    = lane & 15;
    int mt0  = wave << 1;

    // A fragments: direct b128 loads from pre-split matrices
    bf16x8 Ah[2][4], Al[2][4];
    #pragma unroll
    for (int mi = 0; mi < 2; mi++) {
        size_t rowoff = (size_t)(p << 14) + ((mt0 + mi) * 16 + n) * 128 + quad * 8;
        #pragma unroll
        for (int kt = 0; kt < 4; kt++) {
            Ah[mi][kt] = *(const bf16x8*)(Kh + rowoff + kt * 32);
            Al[mi][kt] = *(const bf16x8*)(Kl + rowoff + kt * 32);
        }
    }
    // per-output-row prop constants + phase rotators (f advances 16 per ct)
    float dec_[2][4];
    float pc[2][4], ps[2][4];        // current phase (cos, sin)
    float rc[2][4], rs[2][4];        // step rotator (delta-f = 16)
    #pragma unroll
    for (int mi = 0; mi < 2; mi++)
        #pragma unroll
        for (int r = 0; r < 4; r++) {
            int row = (p << 7) + (mt0 + mi) * 16 + quad * 4 + r;
            dec_[mi][r] = per_row[4*RR + row];
            float tau = per_row[5*RR + row];
            pf_sincos(tau, ct0 * 16 + n, &ps[mi][r], &pc[mi][r]);
            pf_sincos(tau, 16, &rs[mi][r], &rc[mi][r]);
        }

    const u16* pin = in + (size_t)(p << 7) * FPITCH;
    uint4 pk0, pk1;
    int se = tid >> 1, h = tid & 1;      // staging: e-row, 8-complex half
    auto loadTile = [&](int ct) {
        const u16* src = pin + (size_t)se * FPITCH + ct * 32 + h * 16;
        pk0 = *(const uint4*)(src);
        pk1 = *(const uint4*)(src + 8);
    };
    auto writeTile = [&](int buf) {
        unsigned w[8] = {pk0.x, pk0.y, pk0.z, pk0.w, pk1.x, pk1.y, pk1.z, pk1.w};
        int cbase = h * 8;
        #pragma unroll
        for (int k = 0; k < 8; k++) {
            int col = cbase + k;             // w[k] = (re, im) of complex col
            relds[buf][col * EPITCH + se] = (u16)(w[k] & 0xffffu);
            imlds[buf][col * EPITCH + se] = (u16)(w[k] >> 16);
        }
    };

    loadTile(ct0); writeTile(0);
    for (int ct = ct0; ct < ctEnd; ct++) {
        int cb = (ct - ct0) & 1;
        __syncthreads();                    // planes[cb] ready for read
        if (ct + 1 < ctEnd) { loadTile(ct + 1); writeTile(cb ^ 1); }

        f32x4 ar0 = {0.f,0.f,0.f,0.f}, ar1 = {0.f,0.f,0.f,0.f};
        f32x4 ai0 = {0.f,0.f,0.f,0.f}, ai1 = {0.f,0.f,0.f,0.f};
        const u16* vr = &relds[cb][n * EPITCH];
        const u16* vi = &imlds[cb][n * EPITCH];
        #pragma unroll
        for (int kt = 0; kt < 4; kt++) {
            bf16x8 Br = *(const bf16x8*)(vr + kt * 32 + quad * 8);
            bf16x8 Bi = *(const bf16x8*)(vi + kt * 32 + quad * 8);
            ar0 = __builtin_amdgcn_mfma_f32_16x16x32_bf16(Ah[0][kt], Br, ar0, 0,0,0);
            ar1 = __builtin_amdgcn_mfma_f32_16x16x32_bf16(Ah[1][kt], Br, ar1, 0,0,0);
            ai0 = __builtin_amdgcn_mfma_f32_16x16x32_bf16(Ah[0][kt], Bi, ai0, 0,0,0);
            ai1 = __builtin_amdgcn_mfma_f32_16x16x32_bf16(Ah[1][kt], Bi, ai1, 0,0,0);
            ar0 = __builtin_amdgcn_mfma_f32_16x16x32_bf16(Al[0][kt], Br, ar0, 0,0,0);
            ar1 = __builtin_amdgcn_mfma_f32_16x16x32_bf16(Al[1][kt], Br, ar1, 0,0,0);
            ai0 = __builtin_amdgcn_mfma_f32_16x16x32_bf16(Al[0][kt], Bi, ai0, 0,0,0);
            ai1 = __builtin_amdgcn_mfma_f32_16x16x32_bf16(Al[1][kt], Bi, ai1, 0,0,0);
        }

        // prop epilogue: both re and im in-lane -> no shfl; packed store
        int f = ct * 16 + n;                // complex f, < 528
        #pragma unroll
        for (int mi = 0; mi < 2; mi++) {
            f32x4 are = mi ? ar1 : ar0;
            f32x4 aim = mi ? ai1 : ai0;
            #pragma unroll
            for (int r = 0; r < 4; r++) {
                float re = are[r], im = aim[r];
                float s = ps[mi][r], c = pc[mi][r];
                float ore = dec_[mi][r] * (c*re - s*im);
                float oim = dec_[mi][r] * (c*im + s*re);
                int row = (p << 7) + (mt0 + mi) * 16 + quad * 4 + r;
                *(unsigned*)(out + (size_t)row * FPITCH + f * 2) =
                    pack_bf16(ore, oim);
                // advance rotator by delta-f = 16
                float nc = c*rc[mi][r] - s*rs[mi][r];
                float nsv = s*rc[mi][r] + c*rs[mi][r];
                pc[mi][r] = nc; ps[mi][r] = nsv;
            }
        }
    }
}

// ---- segment sum + fused receiver-echo epilogue (bf16 planes).
// 512 blocks x 512 thr = 128 fl x 4 ry; each ry processes 8 rows sequentially
// (max-of-4 Gamma(64) imbalance ~13% vs ~19% at 4 rows). 4 slices/lane + 2x
// edge unroll = 8 loads in flight. Echo partials in registers; one part write
// per block.
__global__ __launch_bounds__(512) void k_segsum(const int* __restrict__ row_start,
                                                const int2* __restrict__ edge,
                                                const u16* __restrict__ in,
                                                u16* __restrict__ outp,
                                                const float* __restrict__ per_row,
                                                float2* __restrict__ part,
                                                int store_cur) {
    __shared__ float2 sh[4][128][5];
    int rb = blockIdx.x;
    int fl = threadIdx.x & 127, ry = threadIdx.x >> 7;
    bool tail = (fl < 8);
    float2 e0 = {0.f,0.f}, e1 = {0.f,0.f}, e2 = {0.f,0.f}, e3 = {0.f,0.f}, e4 = {0.f,0.f};

    for (int i = 0; i < 8; i++) {
        int row = (rb << 5) + (ry << 3) + i;
        int s0 = row_start[row], s1 = row_start[row + 1];
        float a0r=0.f,a0i=0.f,a1r=0.f,a1i=0.f,a2r=0.f,a2i=0.f,a3r=0.f,a3i=0.f;
        float t4r=0.f,t4i=0.f;
        int t = s0;
        for (; t + 1 < s1; t += 2) {
            int2 ed0 = edge[t], ed1 = edge[t+1];
            float v0 = __int_as_float(ed0.y), v1 = __int_as_float(ed1.y);
            const u16* g0p = in + (size_t)ed0.x * FPITCH + (fl << 1);
            const u16* g1p = in + (size_t)ed1.x * FPITCH + (fl << 1);
            unsigned b00 = *(const unsigned*)(g0p);
            unsigned b01 = *(const unsigned*)(g0p + 256);
            unsigned b02 = *(const unsigned*)(g0p + 512);
            unsigned b03 = *(const unsigned*)(g0p + 768);
            unsigned b10 = *(const unsigned*)(g1p);
            unsigned b11 = *(const unsigned*)(g1p + 256);
            unsigned b12 = *(const unsigned*)(g1p + 512);
            unsigned b13 = *(const unsigned*)(g1p + 768);
            a0r = fmaf(v0, bf2f((u16)(b00 & 0xffffu)), a0r); a0i = fmaf(v0, bf2f((u16)(b00 >> 16)), a0i);
            a1r = fmaf(v0, bf2f((u16)(b01 & 0xffffu)), a1r); a1i = fmaf(v0, bf2f((u16)(b01 >> 16)), a1i);
            a2r = fmaf(v0, bf2f((u16)(b02 & 0xffffu)), a2r); a2i = fmaf(v0, bf2f((u16)(b02 >> 16)), a2i);
            a3r = fmaf(v0, bf2f((u16)(b03 & 0xffffu)), a3r); a3i = fmaf(v0, bf2f((u16)(b03 >> 16)), a3i);
            a0r = fmaf(v1, bf2f((u16)(b10 & 0xffffu)), a0r); a0i = fmaf(v1, bf2f((u16)(b10 >> 16)), a0i);
            a1r = fmaf(v1, bf2f((u16)(b11 & 0xffffu)), a1r); a1i = fmaf(v1, bf2f((u16)(b11 >> 16)), a1i);
            a2r = fmaf(v1, bf2f((u16)(b12 & 0xffffu)), a2r); a2i = fmaf(v1, bf2f((u16)(b12 >> 16)), a2i);
            a3r = fmaf(v1, bf2f((u16)(b13 & 0xffffu)), a3r); a3i = fmaf(v1, bf2f((u16)(b13 >> 16)), a3i);
            if (tail) {
                unsigned b04 = *(const unsigned*)(g0p + 1024);
                unsigned b14 = *(const unsigned*)(g1p + 1024);
                t4r = fmaf(v0, bf2f((u16)(b04 & 0xffffu)), t4r); t4i = fmaf(v0, bf2f((u16)(b04 >> 16)), t4i);
                t4r = fmaf(v1, bf2f((u16)(b14 & 0xffffu)), t4r); t4i = fmaf(v1, bf2f((u16)(b14 >> 16)), t4i);
            }
        }
        if (t < s1) {
            int2 ed = edge[t];
            float v = __int_as_float(ed.y);
            const u16* g = in + (size_t)ed.x * FPITCH + (fl << 1);
            unsigned b0 = *(const unsigned*)(g);
            unsigned b1 = *(const unsigned*)(g + 256);
            unsigned b2 = *(const unsigned*)(g + 512);
            unsigned b3 = *(const unsigned*)(g + 768);
            a0r = fmaf(v, bf2f((u16)(b0 & 0xffffu)), a0r); a0i = fmaf(v, bf2f((u16)(b0 >> 16)), a0i);
            a1r = fmaf(v, bf2f((u16)(b1 & 0xffffu)), a1r); a1i = fmaf(v, bf2f((u16)(b1 >> 16)), a1i);
            a2r = fmaf(v, bf2f((u16)(b2 & 0xffffu)), a2r); a2i = fmaf(v, bf2f((u16)(b2 >> 16)), a2i);
            a3r = fmaf(v, bf2f((u16)(b3 & 0xffffu)), a3r); a3i = fmaf(v, bf2f((u16)(b3 >> 16)), a3i);
            if (tail) {
                unsigned b4 = *(const unsigned*)(g + 1024);
                t4r = fmaf(v, bf2f((u16)(b4 & 0xffffu)), t4r); t4i = fmaf(v, bf2f((u16)(b4 >> 16)), t4i);
            }
        }
        if (store_cur) {
            u16* w = outp + (size_t)row * FPITCH + (fl << 1);
            *(unsigned*)(w)       = pack_bf16(a0r, a0i);
            *(unsigned*)(w + 256) = pack_bf16(a1r, a1i);
            *(unsigned*)(w + 512) = pack_bf16(a2r, a2i);
            *(unsigned*)(w + 768) = pack_bf16(a3r, a3i);
            if (tail)
                *(unsigned*)(w + 1024) = pack_bf16(t4r, t4i);
        }
        // echo: contrib(f) = w_rec * phase(tau_rec, f) * value, into registers
        float wr = per_row[2*RR + row], taur = per_row[3*RR + row];
        float s, c;
        pf_sincos(taur, fl, &s, &c);
        e0.x = fmaf(wr, c*a0r - s*a0i, e0.x); e0.y = fmaf(wr, c*a0i + s*a0r, e0.y);
        pf_sincos(taur, fl + 128, &s, &c);
        e1.x = fmaf(wr, c*a1r - s*a1i, e1.x); e1.y = fmaf(wr, c*a1i + s*a1r, e1.y);
        pf_sincos(taur, fl + 256, &s, &c);
        e2.x = fmaf(wr, c*a2r - s*a2i, e2.x); e2.y = fmaf(wr, c*a2i + s*a2r, e2.y);
        pf_sincos(taur, fl + 384, &s, &c);
        e3.x = fmaf(wr, c*a3r - s*a3i, e3.x); e3.y = fmaf(wr, c*a3i + s*a3r, e3.y);
        if (tail && (512 + fl) < FF) {       // f=512 only
            pf_sincos(taur, 512 + fl, &s, &c);
            e4.x = fmaf(wr, c*t4r - s*t4i, e4.x); e4.y = fmaf(wr, c*t4i + s*t4r, e4.y);
        }
    }
    sh[ry][fl][0] = e0; sh[ry][fl][1] = e1; sh[ry][fl][2] = e2;
    sh[ry][fl][3] = e3; sh[ry][fl][4] = e4;
    __syncthreads();
    if (ry == 0) {
        float2* pp = part + (size_t)rb * PSTRIDE;
        #pragma unroll
        for (int sidx = 0; sidx < 5; sidx++) {
            int fidx = sidx * 128 + fl;
            if (fidx < FP) {
                float2 v0 = sh[0][fl][sidx], v1 = sh[1][fl][sidx];
                float2 v2 = sh[2][fl][sidx], v3 = sh[3][fl][sidx];
                float2 acc = pp[fidx];
                acc.x += v0.x + v1.x + v2.x + v3.x;
                acc.y += v0.y + v1.y + v2.y + v3.y;
                pp[fidx] = acc;
            }
        }
    }
}

// ---- fold echo partials: echo[f] += sum_rb part[rb][f]
__global__ __launch_bounds__(256) void k_fold(const float2* __restrict__ part,
                                              float* __restrict__ echo) {
    int f = blockIdx.x;     // 0..FF-1
    float sx = 0.f, sy = 0.f;
    for (int rb = threadIdx.x; rb < NRB; rb += 256) {
        float2 v = part[(size_t)rb * PSTRIDE + f];
        sx += v.x; sy += v.y;
    }
    for (int off = 32; off >= 1; off >>= 1) {
        sx += __shfl_down(sx, off, 64);
        sy += __shfl_down(sy, off, 64);
    }
    __shared__ float red[2][4];
    int lane = threadIdx.x & 63, w = threadIdx.x >> 6;
    if (lane == 0) { red[0][w] = sx; red[1][w] = sy; }
    __syncthreads();
    if (threadIdx.x == 0) {
        sx = red[0][0]+red[0][1]+red[0][2]+red[0][3];
        sy = red[1][0]+red[1][1]+red[1][2]+red[1][3];
        echo[2*f] += sx;
        echo[2*f+1] += sy;
    }
}

// ---- irfft(n=1024) / fsm_window
__global__ void k_irfft(const float* __restrict__ echo, float* __restrict__ out) {
    int t = blockIdx.x * blockDim.x + threadIdx.x;   // 0..1023
    float acc = echo[0];                              // f=0 (real)
    float nyq = echo[2 * 512];                        // Nyquist real part
    acc += (t & 1) ? -nyq : nyq;
    for (int f = 1; f < 512; f++) {
        int m = (f * t) & 1023;
        float ang = (float)m * 0.006135923151542565f;  // 2*pi/1024
        float s, c; __sincosf(ang, &s, &c);
        acc += 2.0f * (echo[2*f]*c - echo[2*f+1]*s);
    }
    acc *= (1.0f / 1024.0f);
    float tsec = (float)t * (1.0f / 16000.0f);
    float win = expf(LOG_GAMMA * tsec);
    out[t] = acc / win;
}

extern "C" void kernel_launch(void* const* d_in, const int* in_sizes, int n_in,
                              void* d_out, int out_size, void* d_ws, size_t ws_size,
                              hipStream_t stream) {
    const float* source_pos   = (const float*)d_in[0];
    const float* receiver_pos = (const float*)d_in[1];
    const float* absorption   = (const float*)d_in[2];
    const float* scattering   = (const float*)d_in[3];
    const float* gk_val       = (const float*)d_in[4];
    const float* basis        = (const float*)d_in[5];
    const float* avg_dist     = (const float*)d_in[6];
    const float* rpos         = (const float*)d_in[7];
    const int*   gk_row       = (const int*)d_in[8];
    const int*   gk_col       = (const int*)d_in[9];
    const int*   object_ids   = (const int*)d_in[10];
    float* out = (float*)d_out;

    char* base = (char*)d_ws;
    size_t off = 0;
    auto alloc = [&](size_t bytes) -> void* {
        void* ptr = base + off;
        off = (off + bytes + 255) & ~(size_t)255;
        return ptr;
    };
    const size_t PLANE = (size_t)RR * FPITCH + FPITCH;   // +1 row slack
    u16*    Kh        = (u16*)alloc(sizeof(u16) * PP * DD * DD);
    u16*    Kl        = (u16*)alloc(sizeof(u16) * PP * DD * DD);
    u16*    cur       = (u16*)alloc(sizeof(u16) * PLANE);
    u16*    nxt       = (u16*)alloc(sizeof(u16) * PLANE);
    float*  per_row   = (float*)alloc(sizeof(float) * 6 * RR);
    int*    row_start = (int*)alloc(sizeof(int) * (RR + 1));
    int*    cursor    = (int*)alloc(sizeof(int) * RR);
    int2*   edge      = (int2*)alloc(sizeof(int2) * EE);
    // part, echo, counts contiguous -> one memset covers all three
    float2* part      = (float2*)alloc(sizeof(float2) * NRB * PSTRIDE);
    float*  echo      = (float*)alloc(sizeof(float) * 1056);
    int*    counts    = (int*)alloc(sizeof(int) * RR);
    size_t  zspan     = (size_t)((char*)(counts + RR) - (char*)part);

    hipMemsetAsync(part, 0, zspan, stream);

    k_setup<<<8768, 256, 0, stream>>>(rpos, source_pos, receiver_pos, avg_dist,
                                      per_row, absorption, scattering,
                                      object_ids, basis, Kh, Kl, gk_row, counts);
    k_scan<<<1, 1024, 0, stream>>>(counts, row_start, cursor);
    k_scatter_init<<<1024, 256, 0, stream>>>(gk_row, gk_val, gk_col, cursor,
                                             edge, per_row, cur, echo);

    for (int b = 0; b < 4; b++) {
        k_matmul<<<512, 256, 0, stream>>>(Kh, Kl, cur, per_row, nxt);
        k_segsum<<<NRB, 512, 0, stream>>>(row_start, edge, nxt, cur,
                                          per_row, part, (b < 3) ? 1 : 0);
    }

    k_fold<<<FF, 256, 0, stream>>>(part, echo);
    k_irfft<<<4, 256, 0, stream>>>(echo, out);
}

// Round 19
// 432.475 us; speedup vs baseline: 1.0753x; 1.0550x over previous
//
#include <hip/hip_runtime.h>
#include <math.h>

#define PP 128
#define DD 128
#define RR 16384
#define EE 131072
#define TT 1024
#define FF 513
#define FP 520          /* logical f count */
#define FPW 528         /* written f count (pad to full pitch; never gathered) */
#define FPITCH 1056     /* u16 per plane row = 528 complex, 64B-line aligned */
#define NRB 1024        /* segsum row-blocks (16 rows each) */
#define PSTRIDE 528     /* part row stride in float2 */
#define EPITCH 136      /* u16 per col-row of split LDS V planes */

#define TAU_SCALE 46.64723032069971    /* SR / C_SOUND */
#define KDECAY   -0.0211392282f        /* LOG_GAMMA/C - AIR */
#define LOG_GAMMA -6.907755278982137f
#define TWO_PI    6.283185307179586

typedef __attribute__((ext_vector_type(8))) short bf16x8;
typedef __attribute__((ext_vector_type(4))) float f32x4;
typedef unsigned short u16;

__device__ __forceinline__ u16 f2bf(float x) {         // RNE float->bf16 bits
    unsigned u = __float_as_uint(x);
    unsigned r = (u + 0x7fffu + ((u >> 16) & 1u)) >> 16;
    return (u16)r;
}
__device__ __forceinline__ float bf2f(u16 b) {
    return __uint_as_float(((unsigned)b) << 16);
}
// packed (re,im) -> dword of two bf16; HW v_cvt_pk_bf16_f32 when available
__device__ __forceinline__ unsigned pack_bf16(float x, float y) {
#if __has_builtin(__builtin_amdgcn_cvt_pk_bf16_f32)
    auto v = __builtin_amdgcn_cvt_pk_bf16_f32(x, y);   // lo=src0, hi=src1
    unsigned u; __builtin_memcpy(&u, &v, sizeof(u));
    return u;
#else
    return (unsigned)f2bf(x) | ((unsigned)f2bf(y) << 16);
#endif
}

// phase = exp(-2*pi*i * tau * f / 1024). Integer-exact mod-1024 reduction:
// tau = ti + tf (Sterbenz-exact), (ti*f) mod 1024 in int, residual tf*f
// in fp32 (abs err ~6e-5 -> ~4e-7 rad). No f64.
__device__ __forceinline__ void pf_sincos(float tau, int f, float* s, float* c) {
    int ti = (int)tau;
    float tf = tau - (float)ti;
    int m = (ti * f) & 1023;
    float u = fmaf(tf, (float)f, (float)m);
    float ang = u * -0.006135923151542565f;          // -2*pi/1024
    __sincosf(ang, s, c);
}

// ---- merged setup: [0,8192) build Kh/Kl (pre-split bf16 hi/lo, fragment
// layout), [8192,8256) per-row precompute, [8256,8768) edge count.
__global__ void k_setup(const float* __restrict__ rpos,
                        const float* __restrict__ spos,
                        const float* __restrict__ cpos,
                        const float* __restrict__ avg_dist,
                        float* __restrict__ per_row,
                        const float* __restrict__ absorption,
                        const float* __restrict__ scattering,
                        const int* __restrict__ object_ids,
                        const float* __restrict__ basis,
                        u16* __restrict__ Kh, u16* __restrict__ Kl,
                        const int* __restrict__ gk_row,
                        int* __restrict__ counts) {
    int b = blockIdx.x;
    if (b < 8192) {
        int idx = b * 256 + threadIdx.x;    // p*16384 + d*128 + e
        int p  = idx >> 14;
        int de = idx & 16383;
        int obj = object_ids[p];
        float refl = 1.0f - absorption[obj];
        float sc   = scattering[obj];
        float kv = refl*sc*basis[de] + refl*(1.0f - sc)*basis[16384 + de];
        u16 hb = f2bf(kv);
        Kh[idx] = hb;
        Kl[idx] = f2bf(kv - bf2f(hb));
    } else if (b < 8256) {
        int r = (b - 8192) * 256 + threadIdx.x;
        float x = rpos[3*r], y = rpos[3*r+1], z = rpos[3*r+2];
        float dx = x - spos[0], dy = y - spos[1], dz = z - spos[2];
        float ds = sqrtf(dx*dx + dy*dy + dz*dz);
        per_row[0*RR + r] = (1.0f/(ds*ds + 0.001f)) * expf(KDECAY * ds);
        per_row[1*RR + r] = ds * (float)TAU_SCALE;
        dx = x - cpos[0]; dy = y - cpos[1]; dz = z - cpos[2];
        float dr = sqrtf(dx*dx + dy*dy + dz*dz);
        per_row[2*RR + r] = (1.0f/(dr*dr + 0.001f)) * expf(KDECAY * dr);
        per_row[3*RR + r] = dr * (float)TAU_SCALE;
        float da = avg_dist[r];
        per_row[4*RR + r] = expf(KDECAY * da);
        per_row[5*RR + r] = da * (float)TAU_SCALE;
    } else {
        int e = (b - 8256) * 256 + threadIdx.x;
        atomicAdd(&counts[gk_row[e]], 1);
    }
}

__global__ __launch_bounds__(1024) void k_scan(const int* __restrict__ counts,
                                               int* __restrict__ row_start,
                                               int* __restrict__ cursor) {
    __shared__ int sh[1024];
    int tid = threadIdx.x;
    int base = tid * 16;
    int local[16];
    int sum = 0;
    #pragma unroll
    for (int j = 0; j < 16; j++) { local[j] = sum; sum += counts[base + j]; }
    sh[tid] = sum;
    __syncthreads();
    for (int off = 1; off < 1024; off <<= 1) {
        int v = (tid >= off) ? sh[tid - off] : 0;
        __syncthreads();
        sh[tid] += v;
        __syncthreads();
    }
    int chunk_excl = sh[tid] - sum;   // exclusive prefix of this 16-chunk
    #pragma unroll
    for (int j = 0; j < 16; j++) {
        int v = chunk_excl + local[j];
        row_start[base + j] = v;
        cursor[base + j] = v;
    }
    if (tid == 1023) row_start[RR] = chunk_excl + sum;
}

// ---- merged scatter + init: blocks [0,512) scatter edges; [512,1024) init.
__global__ __launch_bounds__(256) void k_scatter_init(
                          const int* __restrict__ gk_row,
                          const float* __restrict__ gk_val,
                          const int* __restrict__ gk_col,
                          int* __restrict__ cursor,
                          int2* __restrict__ edge,
                          const float* __restrict__ per_row,
                          u16* __restrict__ cur,
                          float* __restrict__ echo) {
    int b = blockIdx.x;
    if (b < 512) {
        int e = b * 256 + threadIdx.x;
        int pos = atomicAdd(&cursor[gk_row[e]], 1);
        edge[pos] = make_int2(gk_col[e], __float_as_int(gk_val[e]));
        return;
    }
    // ---- init with delta-f=64 rotators: 4 sincos/row (vs 2/element).
    __shared__ float2 sh[4][64][9];
    int fl = threadIdx.x & 63, rg = threadIdx.x >> 6;
    int r0 = (b - 512) * 32;
    float2 eacc[9];
    #pragma unroll
    for (int k = 0; k < 9; k++) eacc[k] = make_float2(0.f, 0.f);

    for (int i = 0; i < 8; i++) {
        int r = r0 + rg + i * 4;
        float amp = per_row[r],      tau  = per_row[RR + r];
        float w   = per_row[2*RR+r], taur = per_row[3*RR + r];
        float s1, c1, rs1, rc1, s2, c2, rs2, rc2;
        pf_sincos(tau,  fl, &s1, &c1);  pf_sincos(tau,  64, &rs1, &rc1);
        pf_sincos(taur, fl, &s2, &c2);  pf_sincos(taur, 64, &rs2, &rc2);
        u16* wrow = cur + (size_t)r * FPITCH;
        #pragma unroll
        for (int k = 0; k < 9; k++) {
            int f = fl + (k << 6);
            float re = amp * c1, im = amp * s1;
            if (f < FPW)
                *(unsigned*)(wrow + f * 2) = pack_bf16(re, im);
            if (f < FF) {
                eacc[k].x = fmaf(w, c2*re - s2*im, eacc[k].x);
                eacc[k].y = fmaf(w, c2*im + s2*re, eacc[k].y);
            }
            float n1c = c1*rc1 - s1*rs1, n1s = s1*rc1 + c1*rs1;
            c1 = n1c; s1 = n1s;
            float n2c = c2*rc2 - s2*rs2, n2s = s2*rc2 + c2*rs2;
            c2 = n2c; s2 = n2s;
        }
    }
    #pragma unroll
    for (int k = 0; k < 9; k++) sh[rg][fl][k] = eacc[k];
    __syncthreads();
    if (rg == 0) {
        #pragma unroll
        for (int k = 0; k < 9; k++) {
            int f = fl + (k << 6);
            if (f < FF) {
                float sx = sh[0][fl][k].x + sh[1][fl][k].x + sh[2][fl][k].x + sh[3][fl][k].x;
                float sy = sh[0][fl][k].y + sh[1][fl][k].y + sh[2][fl][k].y + sh[3][fl][k].y;
                atomicAdd(&echo[2*f],   sx);
                atomicAdd(&echo[2*f+1], sy);
            }
        }
    }
}

// ---- matmul + prop via MFMA, bf16 planes, SPLIT re/im LDS.
// A-fragments loaded DIRECTLY from pre-split Kh/Kl (one b128 each). Grid 512
// = 128 p x 4 chunks (XCD-swizzled on p); chunk q covers 8 complex-tiles ct
// (16 complex f each), q=3 covers 9 (pad cols 520..527 written, never
// gathered). Lane n holds re+im of f=ct*16+n: no-shfl epilogue, packed stores.
__global__ __launch_bounds__(256) void k_matmul(const u16* __restrict__ Kh,
                                                const u16* __restrict__ Kl,
                                                const u16* __restrict__ in,
                                                const float* __restrict__ per_row,
                                                u16* __restrict__ out) {
    __shared__ u16 relds[2][16 * EPITCH];
    __shared__ u16 imlds[2][16 * EPITCH];
    int b = blockIdx.x;
    int xcd = b & 7;
    int g = b >> 3;                  // 0..63
    int p = (g >> 2) * 8 + xcd;
    int q = g & 3;
    int ct0 = q * 8;
    int ctEnd = (q == 3) ? 33 : ct0 + 8;

    int tid  = threadIdx.x;
    int wave = tid >> 6;
    int lane = tid & 63;
    int quad = lane >> 4;
    int n    = lane & 15;
    int mt0  = wave << 1;

    // A fragments: direct b128 loads from pre-split matrices
    bf16x8 Ah[2][4], Al[2][4];
    #pragma unroll
    for (int mi = 0; mi < 2; mi++) {
        size_t rowoff = (size_t)(p << 14) + ((mt0 + mi) * 16 + n) * 128 + quad * 8;
        #pragma unroll
        for (int kt = 0; kt < 4; kt++) {
            Ah[mi][kt] = *(const bf16x8*)(Kh + rowoff + kt * 32);
            Al[mi][kt] = *(const bf16x8*)(Kl + rowoff + kt * 32);
        }
    }
    // per-output-row prop constants + phase rotators (f advances 16 per ct)
    float dec_[2][4];
    float pc[2][4], ps[2][4];        // current phase (cos, sin)
    float rc[2][4], rs[2][4];        // step rotator (delta-f = 16)
    #pragma unroll
    for (int mi = 0; mi < 2; mi++)
        #pragma unroll
        for (int r = 0; r < 4; r++) {
            int row = (p << 7) + (mt0 + mi) * 16 + quad * 4 + r;
            dec_[mi][r] = per_row[4*RR + row];
            float tau = per_row[5*RR + row];
            pf_sincos(tau, ct0 * 16 + n, &ps[mi][r], &pc[mi][r]);
            pf_sincos(tau, 16, &rs[mi][r], &rc[mi][r]);
        }

    const u16* pin = in + (size_t)(p << 7) * FPITCH;
    uint4 pk0, pk1;
    int se = tid >> 1, h = tid & 1;      // staging: e-row, 8-complex half
    auto loadTile = [&](int ct) {
        const u16* src = pin + (size_t)se * FPITCH + ct * 32 + h * 16;
        pk0 = *(const uint4*)(src);
        pk1 = *(const uint4*)(src + 8);
    };
    auto writeTile = [&](int buf) {
        unsigned w[8] = {pk0.x, pk0.y, pk0.z, pk0.w, pk1.x, pk1.y, pk1.z, pk1.w};
        int cbase = h * 8;
        #pragma unroll
        for (int k = 0; k < 8; k++) {
            int col = cbase + k;             // w[k] = (re, im) of complex col
            relds[buf][col * EPITCH + se] = (u16)(w[k] & 0xffffu);
            imlds[buf][col * EPITCH + se] = (u16)(w[k] >> 16);
        }
    };

    loadTile(ct0); writeTile(0);
    for (int ct = ct0; ct < ctEnd; ct++) {
        int cb = (ct - ct0) & 1;
        __syncthreads();                    // planes[cb] ready for read
        if (ct + 1 < ctEnd) { loadTile(ct + 1); writeTile(cb ^ 1); }

        f32x4 ar0 = {0.f,0.f,0.f,0.f}, ar1 = {0.f,0.f,0.f,0.f};
        f32x4 ai0 = {0.f,0.f,0.f,0.f}, ai1 = {0.f,0.f,0.f,0.f};
        const u16* vr = &relds[cb][n * EPITCH];
        const u16* vi = &imlds[cb][n * EPITCH];
        #pragma unroll
        for (int kt = 0; kt < 4; kt++) {
            bf16x8 Br = *(const bf16x8*)(vr + kt * 32 + quad * 8);
            bf16x8 Bi = *(const bf16x8*)(vi + kt * 32 + quad * 8);
            ar0 = __builtin_amdgcn_mfma_f32_16x16x32_bf16(Ah[0][kt], Br, ar0, 0,0,0);
            ar1 = __builtin_amdgcn_mfma_f32_16x16x32_bf16(Ah[1][kt], Br, ar1, 0,0,0);
            ai0 = __builtin_amdgcn_mfma_f32_16x16x32_bf16(Ah[0][kt], Bi, ai0, 0,0,0);
            ai1 = __builtin_amdgcn_mfma_f32_16x16x32_bf16(Ah[1][kt], Bi, ai1, 0,0,0);
            ar0 = __builtin_amdgcn_mfma_f32_16x16x32_bf16(Al[0][kt], Br, ar0, 0,0,0);
            ar1 = __builtin_amdgcn_mfma_f32_16x16x32_bf16(Al[1][kt], Br, ar1, 0,0,0);
            ai0 = __builtin_amdgcn_mfma_f32_16x16x32_bf16(Al[0][kt], Bi, ai0, 0,0,0);
            ai1 = __builtin_amdgcn_mfma_f32_16x16x32_bf16(Al[1][kt], Bi, ai1, 0,0,0);
        }

        // prop epilogue: both re and im in-lane -> no shfl; packed store
        int f = ct * 16 + n;                // complex f, < 528
        #pragma unroll
        for (int mi = 0; mi < 2; mi++) {
            f32x4 are = mi ? ar1 : ar0;
            f32x4 aim = mi ? ai1 : ai0;
            #pragma unroll
            for (int r = 0; r < 4; r++) {
                float re = are[r], im = aim[r];
                float s = ps[mi][r], c = pc[mi][r];
                float ore = dec_[mi][r] * (c*re - s*im);
                float oim = dec_[mi][r] * (c*im + s*re);
                int row = (p << 7) + (mt0 + mi) * 16 + quad * 4 + r;
                *(unsigned*)(out + (size_t)row * FPITCH + f * 2) =
                    pack_bf16(ore, oim);
                // advance rotator by delta-f = 16
                float nc = c*rc[mi][r] - s*rs[mi][r];
                float nsv = s*rc[mi][r] + c*rs[mi][r];
                pc[mi][r] = nc; ps[mi][r] = nsv;
            }
        }
    }
}

// ---- segment sum + fused receiver-echo epilogue (bf16 planes, R12-proven
// shape: 1024 blocks x 512 thr = 128 fl x 4 ry, 4 rows/ry -> 4 blocks/CU +
// 8 loads in flight; both halves of the latency-hiding budget satisfied).
__global__ __launch_bounds__(512) void k_segsum(const int* __restrict__ row_start,
                                                const int2* __restrict__ edge,
                                                const u16* __restrict__ in,
                                                u16* __restrict__ outp,
                                                const float* __restrict__ per_row,
                                                float2* __restrict__ part,
                                                int store_cur) {
    __shared__ float2 sh[4][128][5];
    int rb = blockIdx.x;
    int fl = threadIdx.x & 127, ry = threadIdx.x >> 7;
    bool tail = (fl < 8);
    float2 e0 = {0.f,0.f}, e1 = {0.f,0.f}, e2 = {0.f,0.f}, e3 = {0.f,0.f}, e4 = {0.f,0.f};

    for (int i = 0; i < 4; i++) {
        int row = (rb << 4) + (ry << 2) + i;
        int s0 = row_start[row], s1 = row_start[row + 1];
        float a0r=0.f,a0i=0.f,a1r=0.f,a1i=0.f,a2r=0.f,a2i=0.f,a3r=0.f,a3i=0.f;
        float t4r=0.f,t4i=0.f;
        int t = s0;
        for (; t + 1 < s1; t += 2) {
            int2 ed0 = edge[t], ed1 = edge[t+1];
            float v0 = __int_as_float(ed0.y), v1 = __int_as_float(ed1.y);
            const u16* g0p = in + (size_t)ed0.x * FPITCH + (fl << 1);
            const u16* g1p = in + (size_t)ed1.x * FPITCH + (fl << 1);
            unsigned b00 = *(const unsigned*)(g0p);
            unsigned b01 = *(const unsigned*)(g0p + 256);
            unsigned b02 = *(const unsigned*)(g0p + 512);
            unsigned b03 = *(const unsigned*)(g0p + 768);
            unsigned b10 = *(const unsigned*)(g1p);
            unsigned b11 = *(const unsigned*)(g1p + 256);
            unsigned b12 = *(const unsigned*)(g1p + 512);
            unsigned b13 = *(const unsigned*)(g1p + 768);
            a0r = fmaf(v0, bf2f((u16)(b00 & 0xffffu)), a0r); a0i = fmaf(v0, bf2f((u16)(b00 >> 16)), a0i);
            a1r = fmaf(v0, bf2f((u16)(b01 & 0xffffu)), a1r); a1i = fmaf(v0, bf2f((u16)(b01 >> 16)), a1i);
            a2r = fmaf(v0, bf2f((u16)(b02 & 0xffffu)), a2r); a2i = fmaf(v0, bf2f((u16)(b02 >> 16)), a2i);
            a3r = fmaf(v0, bf2f((u16)(b03 & 0xffffu)), a3r); a3i = fmaf(v0, bf2f((u16)(b03 >> 16)), a3i);
            a0r = fmaf(v1, bf2f((u16)(b10 & 0xffffu)), a0r); a0i = fmaf(v1, bf2f((u16)(b10 >> 16)), a0i);
            a1r = fmaf(v1, bf2f((u16)(b11 & 0xffffu)), a1r); a1i = fmaf(v1, bf2f((u16)(b11 >> 16)), a1i);
            a2r = fmaf(v1, bf2f((u16)(b12 & 0xffffu)), a2r); a2i = fmaf(v1, bf2f((u16)(b12 >> 16)), a2i);
            a3r = fmaf(v1, bf2f((u16)(b13 & 0xffffu)), a3r); a3i = fmaf(v1, bf2f((u16)(b13 >> 16)), a3i);
            if (tail) {
                unsigned b04 = *(const unsigned*)(g0p + 1024);
                unsigned b14 = *(const unsigned*)(g1p + 1024);
                t4r = fmaf(v0, bf2f((u16)(b04 & 0xffffu)), t4r); t4i = fmaf(v0, bf2f((u16)(b04 >> 16)), t4i);
                t4r = fmaf(v1, bf2f((u16)(b14 & 0xffffu)), t4r); t4i = fmaf(v1, bf2f((u16)(b14 >> 16)), t4i);
            }
        }
        if (t < s1) {
            int2 ed = edge[t];
            float v = __int_as_float(ed.y);
            const u16* g = in + (size_t)ed.x * FPITCH + (fl << 1);
            unsigned b0 = *(const unsigned*)(g);
            unsigned b1 = *(const unsigned*)(g + 256);
            unsigned b2 = *(const unsigned*)(g + 512);
            unsigned b3 = *(const unsigned*)(g + 768);
            a0r = fmaf(v, bf2f((u16)(b0 & 0xffffu)), a0r); a0i = fmaf(v, bf2f((u16)(b0 >> 16)), a0i);
            a1r = fmaf(v, bf2f((u16)(b1 & 0xffffu)), a1r); a1i = fmaf(v, bf2f((u16)(b1 >> 16)), a1i);
            a2r = fmaf(v, bf2f((u16)(b2 & 0xffffu)), a2r); a2i = fmaf(v, bf2f((u16)(b2 >> 16)), a2i);
            a3r = fmaf(v, bf2f((u16)(b3 & 0xffffu)), a3r); a3i = fmaf(v, bf2f((u16)(b3 >> 16)), a3i);
            if (tail) {
                unsigned b4 = *(const unsigned*)(g + 1024);
                t4r = fmaf(v, bf2f((u16)(b4 & 0xffffu)), t4r); t4i = fmaf(v, bf2f((u16)(b4 >> 16)), t4i);
            }
        }
        if (store_cur) {
            u16* w = outp + (size_t)row * FPITCH + (fl << 1);
            *(unsigned*)(w)       = pack_bf16(a0r, a0i);
            *(unsigned*)(w + 256) = pack_bf16(a1r, a1i);
            *(unsigned*)(w + 512) = pack_bf16(a2r, a2i);
            *(unsigned*)(w + 768) = pack_bf16(a3r, a3i);
            if (tail)
                *(unsigned*)(w + 1024) = pack_bf16(t4r, t4i);
        }
        // echo: contrib(f) = w_rec * phase(tau_rec, f) * value, into registers
        float wr = per_row[2*RR + row], taur = per_row[3*RR + row];
        float s, c;
        pf_sincos(taur, fl, &s, &c);
        e0.x = fmaf(wr, c*a0r - s*a0i, e0.x); e0.y = fmaf(wr, c*a0i + s*a0r, e0.y);
        pf_sincos(taur, fl + 128, &s, &c);
        e1.x = fmaf(wr, c*a1r - s*a1i, e1.x); e1.y = fmaf(wr, c*a1i + s*a1r, e1.y);
        pf_sincos(taur, fl + 256, &s, &c);
        e2.x = fmaf(wr, c*a2r - s*a2i, e2.x); e2.y = fmaf(wr, c*a2i + s*a2r, e2.y);
        pf_sincos(taur, fl + 384, &s, &c);
        e3.x = fmaf(wr, c*a3r - s*a3i, e3.x); e3.y = fmaf(wr, c*a3i + s*a3r, e3.y);
        if (tail && (512 + fl) < FF) {       // f=512 only
            pf_sincos(taur, 512 + fl, &s, &c);
            e4.x = fmaf(wr, c*t4r - s*t4i, e4.x); e4.y = fmaf(wr, c*t4i + s*t4r, e4.y);
        }
    }
    sh[ry][fl][0] = e0; sh[ry][fl][1] = e1; sh[ry][fl][2] = e2;
    sh[ry][fl][3] = e3; sh[ry][fl][4] = e4;
    __syncthreads();
    if (ry == 0) {
        float2* pp = part + (size_t)rb * PSTRIDE;
        #pragma unroll
        for (int sidx = 0; sidx < 5; sidx++) {
            int fidx = sidx * 128 + fl;
            if (fidx < FP) {
                float2 v0 = sh[0][fl][sidx], v1 = sh[1][fl][sidx];
                float2 v2 = sh[2][fl][sidx], v3 = sh[3][fl][sidx];
                float2 acc = pp[fidx];
                acc.x += v0.x + v1.x + v2.x + v3.x;
                acc.y += v0.y + v1.y + v2.y + v3.y;
                pp[fidx] = acc;
            }
        }
    }
}

// ---- fold echo partials: echo[f] += sum_rb part[rb][f]
__global__ __launch_bounds__(256) void k_fold(const float2* __restrict__ part,
                                              float* __restrict__ echo) {
    int f = blockIdx.x;     // 0..FF-1
    float sx = 0.f, sy = 0.f;
    for (int rb = threadIdx.x; rb < NRB; rb += 256) {
        float2 v = part[(size_t)rb * PSTRIDE + f];
        sx += v.x; sy += v.y;
    }
    for (int off = 32; off >= 1; off >>= 1) {
        sx += __shfl_down(sx, off, 64);
        sy += __shfl_down(sy, off, 64);
    }
    __shared__ float red[2][4];
    int lane = threadIdx.x & 63, w = threadIdx.x >> 6;
    if (lane == 0) { red[0][w] = sx; red[1][w] = sy; }
    __syncthreads();
    if (threadIdx.x == 0) {
        sx = red[0][0]+red[0][1]+red[0][2]+red[0][3];
        sy = red[1][0]+red[1][1]+red[1][2]+red[1][3];
        echo[2*f] += sx;
        echo[2*f+1] += sy;
    }
}

// ---- irfft(n=1024) / fsm_window
__global__ void k_irfft(const float* __restrict__ echo, float* __restrict__ out) {
    int t = blockIdx.x * blockDim.x + threadIdx.x;   // 0..1023
    float acc = echo[0];                              // f=0 (real)
    float nyq = echo[2 * 512];                        // Nyquist real part
    acc += (t & 1) ? -nyq : nyq;
    for (int f = 1; f < 512; f++) {
        int m = (f * t) & 1023;
        float ang = (float)m * 0.006135923151542565f;  // 2*pi/1024
        float s, c; __sincosf(ang, &s, &c);
        acc += 2.0f * (echo[2*f]*c - echo[2*f+1]*s);
    }
    acc *= (1.0f / 1024.0f);
    float tsec = (float)t * (1.0f / 16000.0f);
    float win = expf(LOG_GAMMA * tsec);
    out[t] = acc / win;
}

extern "C" void kernel_launch(void* const* d_in, const int* in_sizes, int n_in,
                              void* d_out, int out_size, void* d_ws, size_t ws_size,
                              hipStream_t stream) {
    const float* source_pos   = (const float*)d_in[0];
    const float* receiver_pos = (const float*)d_in[1];
    const float* absorption   = (const float*)d_in[2];
    const float* scattering   = (const float*)d_in[3];
    const float* gk_val       = (const float*)d_in[4];
    const float* basis        = (const float*)d_in[5];
    const float* avg_dist     = (const float*)d_in[6];
    const float* rpos         = (const float*)d_in[7];
    const int*   gk_row       = (const int*)d_in[8];
    const int*   gk_col       = (const int*)d_in[9];
    const int*   object_ids   = (const int*)d_in[10];
    float* out = (float*)d_out;

    char* base = (char*)d_ws;
    size_t off = 0;
    auto alloc = [&](size_t bytes) -> void* {
        void* ptr = base + off;
        off = (off + bytes + 255) & ~(size_t)255;
        return ptr;
    };
    const size_t PLANE = (size_t)RR * FPITCH + FPITCH;   // +1 row slack
    u16*    Kh        = (u16*)alloc(sizeof(u16) * PP * DD * DD);
    u16*    Kl        = (u16*)alloc(sizeof(u16) * PP * DD * DD);
    u16*    cur       = (u16*)alloc(sizeof(u16) * PLANE);
    u16*    nxt       = (u16*)alloc(sizeof(u16) * PLANE);
    float*  per_row   = (float*)alloc(sizeof(float) * 6 * RR);
    int*    row_start = (int*)alloc(sizeof(int) * (RR + 1));
    int*    cursor    = (int*)alloc(sizeof(int) * RR);
    int2*   edge      = (int2*)alloc(sizeof(int2) * EE);
    // part, echo, counts contiguous -> one memset covers all three
    float2* part      = (float2*)alloc(sizeof(float2) * NRB * PSTRIDE);
    float*  echo      = (float*)alloc(sizeof(float) * 1056);
    int*    counts    = (int*)alloc(sizeof(int) * RR);
    size_t  zspan     = (size_t)((char*)(counts + RR) - (char*)part);

    hipMemsetAsync(part, 0, zspan, stream);

    k_setup<<<8768, 256, 0, stream>>>(rpos, source_pos, receiver_pos, avg_dist,
                                      per_row, absorption, scattering,
                                      object_ids, basis, Kh, Kl, gk_row, counts);
    k_scan<<<1, 1024, 0, stream>>>(counts, row_start, cursor);
    k_scatter_init<<<1024, 256, 0, stream>>>(gk_row, gk_val, gk_col, cursor,
                                             edge, per_row, cur, echo);

    for (int b = 0; b < 4; b++) {
        k_matmul<<<512, 256, 0, stream>>>(Kh, Kl, cur, per_row, nxt);
        k_segsum<<<NRB, 512, 0, stream>>>(row_start, edge, nxt, cur,
                                          per_row, part, (b < 3) ? 1 : 0);
    }

    k_fold<<<FF, 256, 0, stream>>>(part, echo);
    k_irfft<<<4, 256, 0, stream>>>(echo, out);
}